// Round 1
// baseline (679.198 us; speedup 1.0000x reference)
//
#include <hip/hip_runtime.h>
#include <math.h>

// Problem constants (B, N, D_IN, D_STATE) = (32, 4096, 1024, 1024).
// softmax is shift-invariant, so the hidden@w_h + b term (constant over n)
// cancels exactly — only x@w_x matters.
#define N_SZ 4096
#define D_SZ 1024

// Kernel 1: logits[row] = dot(x[row, 0:1024], w_x).  One wave (64 lanes) per
// row; lane l reads 4 float4s (16 floats) at coalesced 16B/lane offsets.
// w_x fragment is loaded once per persistent wave and reused across rows.
__global__ __launch_bounds__(256) void logits_k(
    const float* __restrict__ x, const float* __restrict__ wx,
    float* __restrict__ out, int nrows)
{
    const int lane = threadIdx.x & 63;
    const int wid  = blockIdx.x * (blockDim.x >> 6) + (threadIdx.x >> 6);
    const int nw   = gridDim.x * (blockDim.x >> 6);

    const float4* w4 = (const float4*)wx;
    const float4 w0 = w4[lane];
    const float4 w1 = w4[64  + lane];
    const float4 w2 = w4[128 + lane];
    const float4 w3 = w4[192 + lane];

    for (int row = wid; row < nrows; row += nw) {
        const float4* xr = (const float4*)(x + (size_t)row * D_SZ);
        const float4 a0 = xr[lane];
        const float4 a1 = xr[64  + lane];
        const float4 a2 = xr[128 + lane];
        const float4 a3 = xr[192 + lane];

        float s = 0.0f;
        s = fmaf(a0.x, w0.x, s); s = fmaf(a0.y, w0.y, s);
        s = fmaf(a0.z, w0.z, s); s = fmaf(a0.w, w0.w, s);
        s = fmaf(a1.x, w1.x, s); s = fmaf(a1.y, w1.y, s);
        s = fmaf(a1.z, w1.z, s); s = fmaf(a1.w, w1.w, s);
        s = fmaf(a2.x, w2.x, s); s = fmaf(a2.y, w2.y, s);
        s = fmaf(a2.z, w2.z, s); s = fmaf(a2.w, w2.w, s);
        s = fmaf(a3.x, w3.x, s); s = fmaf(a3.y, w3.y, s);
        s = fmaf(a3.z, w3.z, s); s = fmaf(a3.w, w3.w, s);

        #pragma unroll
        for (int off = 32; off > 0; off >>= 1)
            s += __shfl_down(s, off, 64);

        if (lane == 0) out[row] = s;
    }
}

// Kernel 2: in-place softmax over N=4096 per batch row. One block (256 thr)
// per row; 16 logits/thread held in registers so the row is read once.
__global__ __launch_bounds__(256) void softmax_k(float* __restrict__ io)
{
    float* row = io + (size_t)blockIdx.x * N_SZ;
    const int tid  = threadIdx.x;
    const int lane = tid & 63;
    const int wv   = tid >> 6;
    __shared__ float sred[4];

    float v[16];
    float m = -INFINITY;
    #pragma unroll
    for (int j = 0; j < 16; ++j) {
        v[j] = row[tid + j * 256];
        m = fmaxf(m, v[j]);
    }
    #pragma unroll
    for (int off = 32; off > 0; off >>= 1)
        m = fmaxf(m, __shfl_down(m, off, 64));
    if (lane == 0) sred[wv] = m;
    __syncthreads();
    m = fmaxf(fmaxf(sred[0], sred[1]), fmaxf(sred[2], sred[3]));
    __syncthreads();   // sred about to be reused

    float s = 0.0f;
    #pragma unroll
    for (int j = 0; j < 16; ++j) {
        v[j] = expf(v[j] - m);
        s += v[j];
    }
    #pragma unroll
    for (int off = 32; off > 0; off >>= 1)
        s += __shfl_down(s, off, 64);
    if (lane == 0) sred[wv] = s;
    __syncthreads();
    s = sred[0] + sred[1] + sred[2] + sred[3];

    const float inv = 1.0f / s;
    #pragma unroll
    for (int j = 0; j < 16; ++j)
        row[tid + j * 256] = v[j] * inv;
}

extern "C" void kernel_launch(void* const* d_in, const int* in_sizes, int n_in,
                              void* d_out, int out_size, void* d_ws, size_t ws_size,
                              hipStream_t stream) {
    const float* x  = (const float*)d_in[0];   // fixed_inputs [32,4096,1024]
    const float* wx = (const float*)d_in[2];   // w_x [1024]
    // d_in[1] (hidden), d_in[3] (w_h), d_in[4] (b) cancel under softmax.
    float* out = (float*)d_out;                // [32,4096] fp32

    const int nrows = out_size;                // 131072 = B*N
    logits_k<<<2048, 256, 0, stream>>>(x, wx, out, nrows);
    softmax_k<<<nrows / N_SZ, 256, 0, stream>>>(out);
}